// Round 1
// baseline (18421.205 us; speedup 1.0000x reference)
//
#include <hip/hip_runtime.h>

// HiPPO-LegS forward scan: x_t = A_t x_{t-1} + B_t * inp[t,b], out[t,b,:] = x_t
// L=1024, BATCH=256, N=256. A_t is (N,N) fp32, lower-triangular (upper ~1e-13 junk).
//
// Strategy (round 1, fp32-exact):
//  - 128 WGs x 512 threads; WG owns BB=2 batches, full state x[N][BB] in LDS (ping-pong).
//  - thread = (rowgroup g: 8 rows, kseg s: 4x4 k-chunks strided 64) -> coalesced
//    float4 A loads straight to VGPRs (no LDS staging of A => no LDS BW floor).
//  - triangular skip: chunk loaded only if k0 <= row (exec-masked), else zeros.
//  - per-step: compute partials -> LDS reduce over 16 ksegs -> + input term -> write
//    x_next and out. 2 barriers/step, no inter-WG communication (batches independent).

#define LSTEPS   1024
#define BATCH    256
#define NDIM     256
#define NWG      128   // workgroups; BB = BATCH/NWG
#define BB       2     // batches per WG
#define THREADS  512   // 8 waves
#define XSTRIDE  5     // floats per k-row in x buffers (odd => bank spread)
#define PSEG     514   // partials: per-seg stride in floats (512 + 2 pad)

__global__ __launch_bounds__(THREADS)
void hippo_scan(const float* __restrict__ inp,   // (L, BATCH)
                const float* __restrict__ A,     // (L, N, N)
                const float* __restrict__ Bst,   // (L, N)
                float* __restrict__ out)         // (L, BATCH, N)
{
    __shared__ float xbuf[2][NDIM * XSTRIDE];    // x state, ping-pong: [k][b + pad]
    __shared__ float part[16 * PSEG];            // k-partials: [seg][row*2 + b]

    const int T     = threadIdx.x;
    const int g     = T >> 4;      // 0..31 rowgroup (8 rows each)
    const int s     = T & 15;      // 0..15 k-segment
    const int rbase = g * 8;
    const int b0    = blockIdx.x * BB;
    // reduce-pass mapping: waves 0-3 handle b=0 (rows 0..255), waves 4-7 b=1
    const int rR = T & 255;
    const int bR = T >> 8;

    for (int i = T; i < NDIM * XSTRIDE; i += THREADS) {
        xbuf[0][i] = 0.f;
        xbuf[1][i] = 0.f;
    }
    __syncthreads();

    for (int t = 0; t < LSTEPS; ++t) {
        const float* __restrict__ At = A + (size_t)t * (NDIM * NDIM);
        const float* __restrict__ xc = xbuf[t & 1];
        float* __restrict__ xn       = xbuf[(t & 1) ^ 1];

        float acc[8][BB];
#pragma unroll
        for (int i = 0; i < 8; ++i)
#pragma unroll
            for (int b = 0; b < BB; ++b) acc[i][b] = 0.f;

#pragma unroll
        for (int j = 0; j < 4; ++j) {
            const int k0 = j * 64 + s * 4;       // this thread's 4-wide k-chunk
            // broadcast-read x[k0..k0+3][0..BB-1] from LDS (stride-5 => spread banks)
            float xv[4][BB];
#pragma unroll
            for (int c = 0; c < 4; ++c)
#pragma unroll
                for (int b = 0; b < BB; ++b)
                    xv[c][b] = xc[(k0 + c) * XSTRIDE + b];

#pragma unroll
            for (int i = 0; i < 8; ++i) {
                const int r = rbase + i;
                float4 a = make_float4(0.f, 0.f, 0.f, 0.f);
                if (k0 <= r)                      // triangular skip (exec-masked load)
                    a = *(const float4*)(At + (size_t)r * NDIM + k0);
#pragma unroll
                for (int b = 0; b < BB; ++b) {
                    acc[i][b] += a.x * xv[0][b];
                    acc[i][b] += a.y * xv[1][b];
                    acc[i][b] += a.z * xv[2][b];
                    acc[i][b] += a.w * xv[3][b];
                }
            }
        }

        // stash k-partials: part[s][r][b]
#pragma unroll
        for (int i = 0; i < 8; ++i) {
            const int r = rbase + i;
#pragma unroll
            for (int b = 0; b < BB; ++b)
                part[s * PSEG + r * 2 + b] = acc[i][b];
        }
        __syncthreads();

        // reduce over 16 k-segments, add input term, write x_next and output
        {
            float v = 0.f;
#pragma unroll
            for (int ss = 0; ss < 16; ++ss)
                v += part[ss * PSEG + rR * 2 + bR];
            v += inp[t * BATCH + b0 + bR] * Bst[t * NDIM + rR];
            xn[rR * XSTRIDE + bR] = v;
            out[(size_t)t * (BATCH * NDIM) + (size_t)(b0 + bR) * NDIM + rR] = v;
        }
        __syncthreads();
    }
}

extern "C" void kernel_launch(void* const* d_in, const int* in_sizes, int n_in,
                              void* d_out, int out_size, void* d_ws, size_t ws_size,
                              hipStream_t stream) {
    const float* inp = (const float*)d_in[0];  // (L, BATCH) f32
    const float* A   = (const float*)d_in[1];  // (L, N, N)  f32
    const float* Bst = (const float*)d_in[2];  // (L, N)     f32
    float* out = (float*)d_out;                // (L, BATCH, N) f32
    hipLaunchKernelGGL(hippo_scan, dim3(NWG), dim3(THREADS), 0, stream,
                       inp, A, Bst, out);
}

// Round 2
// 10585.625 us; speedup vs baseline: 1.7402x; 1.7402x over previous
//
#include <hip/hip_runtime.h>

// HiPPO-LegS forward scan: x_t = A_t x_{t-1} + B_t * inp[t,b], out[t,b,:] = x_t
// L=1024, BATCH=256, N=256, fp32. A_t lower-triangular (upper ~1e-13 junk, skipped).
//
// Round 2: latency fix.
//  - 128 WGs x 512 thr, BB=2 batches/WG; thread=(rowgroup g x kseg s) as before.
//  - A chunks for step t live in a 32x float4 register buffer; while consuming
//    them we issue the (exec-masked) loads for step t+1 into the same regs.
//  - Barrier is raw s_barrier preceded by lgkmcnt(0) ONLY -> prefetch global
//    loads stay in flight across the barrier (no vmcnt(0) drain).
//  - 1 barrier/step: k-segment reduction via 4-stage shfl_xor butterfly that
//    also redistributes ownership: lane s ends with (row rbase+(s>>1), b=s&1).
//  - x state: 2 ping-pong buffers of [BB][260] floats -> ds_read_b128 x-reads.

#define LSTEPS   1024
#define BATCH    256
#define NDIM     256
#define NWG      128
#define BB       2
#define THREADS  512
#define XPLANE   260   // floats per batch plane (256 + 4 pad, keeps 16B align)

__global__ __launch_bounds__(THREADS, 2)
void hippo_scan(const float* __restrict__ inp,   // (L, BATCH)
                const float* __restrict__ A,     // (L, N, N)
                const float* __restrict__ Bst,   // (L, N)
                float* __restrict__ out)         // (L, BATCH, N)
{
    __shared__ __align__(16) float xs[2][BB][XPLANE];

    const int T     = threadIdx.x;
    const int g     = T >> 4;        // 0..31 row-group (8 rows)
    const int s     = T & 15;        // 0..15 k-segment
    const int rbase = g * 8;
    const int b0    = blockIdx.x * BB;
    const int rW    = rbase + (s >> 1);  // row this lane owns after reduce
    const int bW    = s & 1;             // batch this lane owns after reduce

    // zero both state buffers (x_{-1} = 0)
    for (int i = T; i < 2 * BB * XPLANE; i += THREADS)
        ((float*)xs)[i] = 0.f;

    // per-thread A base for its chunk set; chunk (j,i) at offset i*NDIM + j*64
    const float* Acur = A + (size_t)rbase * NDIM + s * 4;

    // prologue: load A_0 chunks into the register buffer (masked triangular)
    float4 ab[4][8];
#pragma unroll
    for (int j = 0; j < 4; ++j) {
        const int k0 = j * 64 + s * 4;
#pragma unroll
        for (int i = 0; i < 8; ++i) {
            ab[j][i] = make_float4(0.f, 0.f, 0.f, 0.f);
            if (k0 <= rbase + i)
                ab[j][i] = *(const float4*)(Acur + i * NDIM + j * 64);
        }
    }
    float bst_c = Bst[rW];            // Bst[0][rW]
    float inp_c = inp[b0 + bW];       // inp[0][b0+bW]

    float* outp = out + (size_t)(b0 + bW) * NDIM + rW;

    __syncthreads();   // full drain once: init + prologue visible

    for (int t = 0; t < LSTEPS; ++t) {
        const int cur = t & 1;
        const float* Anext = Acur + (t + 1 < LSTEPS ? NDIM * NDIM : 0);

        float acc[8][BB];
#pragma unroll
        for (int i = 0; i < 8; ++i)
#pragma unroll
            for (int b = 0; b < BB; ++b) acc[i][b] = 0.f;

#pragma unroll
        for (int j = 0; j < 4; ++j) {
            const int k0 = j * 64 + s * 4;
            const float4 xv0 = *(const float4*)&xs[cur][0][k0];
            const float4 xv1 = *(const float4*)&xs[cur][1][k0];
#pragma unroll
            for (int i = 0; i < 8; ++i) {
                const float4 a = ab[j][i];
                if (k0 <= rbase + i)                 // prefetch A_{t+1} chunk
                    ab[j][i] = *(const float4*)(Anext + i * NDIM + j * 64);
                acc[i][0] = fmaf(a.x, xv0.x, acc[i][0]);
                acc[i][0] = fmaf(a.y, xv0.y, acc[i][0]);
                acc[i][0] = fmaf(a.z, xv0.z, acc[i][0]);
                acc[i][0] = fmaf(a.w, xv0.w, acc[i][0]);
                acc[i][1] = fmaf(a.x, xv1.x, acc[i][1]);
                acc[i][1] = fmaf(a.y, xv1.y, acc[i][1]);
                acc[i][1] = fmaf(a.z, xv1.z, acc[i][1]);
                acc[i][1] = fmaf(a.w, xv1.w, acc[i][1]);
            }
        }
        Acur = Anext;

        // prefetch next-step scalars (clamped at the tail; reload is harmless)
        const int tn = (t + 1 < LSTEPS) ? t + 1 : LSTEPS - 1;
        const float bst_n = Bst[tn * NDIM + rW];
        const float inp_n = inp[tn * BATCH + b0 + bW];

        // 4-stage butterfly over the 16-lane k-segment group; simultaneously
        // redistributes so lane s ends with the full sum for (rW, bW).
        float c8[8];
#pragma unroll
        for (int i = 0; i < 8; ++i) {
            const float keep = bW ? acc[i][1] : acc[i][0];
            const float send = bW ? acc[i][0] : acc[i][1];
            c8[i] = keep + __shfl_xor(send, 1);
        }
        float d4[4];
#pragma unroll
        for (int i = 0; i < 4; ++i) {
            const float keep = (s & 2) ? c8[2 * i + 1] : c8[2 * i];
            const float send = (s & 2) ? c8[2 * i]     : c8[2 * i + 1];
            d4[i] = keep + __shfl_xor(send, 2);
        }
        float e2[2];
#pragma unroll
        for (int i = 0; i < 2; ++i) {
            const float keep = (s & 4) ? d4[2 * i + 1] : d4[2 * i];
            const float send = (s & 4) ? d4[2 * i]     : d4[2 * i + 1];
            e2[i] = keep + __shfl_xor(send, 4);
        }
        {
            const float keep = (s & 8) ? e2[1] : e2[0];
            const float send = (s & 8) ? e2[0] : e2[1];
            float v = keep + __shfl_xor(send, 8);

            v = fmaf(inp_c, bst_c, v);

            xs[cur ^ 1][bW][rW] = v;   // state for step t+1
            *outp = v;                 // out[t][b0+bW][rW]
        }
        outp += BATCH * NDIM;
        bst_c = bst_n;
        inp_c = inp_n;

        // drain LDS writes only; A prefetch stays in flight across barrier
        asm volatile("s_waitcnt lgkmcnt(0)" ::: "memory");
        __builtin_amdgcn_s_barrier();
        asm volatile("" ::: "memory");
    }
}

extern "C" void kernel_launch(void* const* d_in, const int* in_sizes, int n_in,
                              void* d_out, int out_size, void* d_ws, size_t ws_size,
                              hipStream_t stream) {
    const float* inp = (const float*)d_in[0];  // (L, BATCH) f32
    const float* A   = (const float*)d_in[1];  // (L, N, N)  f32
    const float* Bst = (const float*)d_in[2];  // (L, N)     f32
    float* out = (float*)d_out;                // (L, BATCH, N) f32
    hipLaunchKernelGGL(hippo_scan, dim3(NWG), dim3(THREADS), 0, stream,
                       inp, A, Bst, out);
}

// Round 3
// 8171.423 us; speedup vs baseline: 2.2543x; 1.2954x over previous
//
#include <hip/hip_runtime.h>

// HiPPO-LegS forward scan: x_t = A_t x_{t-1} + B_t * inp[t,b], out[t,b,:] = x_t
// L=1024, BATCH=256, N=256, fp32. A_t lower-triangular (upper ~1e-13 junk, skipped).
//
// Round 3: TLP fix. Round 2 showed the compiler won't hold a 128-reg A prefetch
// buffer (VGPR_Count=128, VALUBusy 7.3%) and 2 waves/SIMD can't hide latency.
//  - 128 WGs x 1024 threads = 16 waves/CU (4/SIMD), 1 WG/CU. VGPR kept <=128
//    via __launch_bounds__(1024,4) and a small (16 x float4) per-step A buffer.
//  - thread = (g: 4 rows, s: 16 k-segs), BB=2 batches/WG. All 16 tri-masked
//    A float4 loads issue at step top -> 16-deep MLP per wave, 4-way TLP/SIMD.
//  - k-reduction + ownership redistribution via 4-stage shfl_xor butterfly
//    (4 rows x 2 b = 8 owners per 16-lane group; lanes s>=8 duplicate, s<8 write).
//  - 1 barrier/step: raw s_barrier preceded by lgkmcnt(0) only (no vmcnt drain).

#define LSTEPS   1024
#define BATCH    256
#define NDIM     256
#define NWG      128
#define BB       2
#define THREADS  1024
#define XPLANE   260   // floats per batch plane (256 + 4 pad; 1040B = 16B-aligned)

__global__ __launch_bounds__(THREADS, 4)
void hippo_scan(const float* __restrict__ inp,   // (L, BATCH)
                const float* __restrict__ A,     // (L, N, N)
                const float* __restrict__ Bst,   // (L, N)
                float* __restrict__ out)         // (L, BATCH, N)
{
    __shared__ __align__(16) float xs[2][BB][XPLANE];

    const int T     = threadIdx.x;
    const int g     = T >> 4;        // 0..63 row-group (4 rows)
    const int s     = T & 15;        // 0..15 k-segment
    const int rbase = g * 4;
    const int b0    = blockIdx.x * BB;
    const int sel1  = (s >> 1) & 1;  // row bit0 kept after stage 2
    const int sel2  = (s >> 2) & 1;  // row bit1 kept after stage 3
    const int rowOwn = rbase + (sel1 | (sel2 << 1));
    const int bOwn   = s & 1;
    const bool writer = (s < 8);     // s>=8 holds a duplicate of (rowOwn,bOwn)

    // zero both state buffers (x_{-1} = 0)
    for (int i = T; i < 2 * BB * XPLANE; i += THREADS)
        ((float*)xs)[i] = 0.f;

    float bst_c = Bst[rowOwn];            // Bst[0][rowOwn]
    float inp_c = inp[b0 + bOwn];         // inp[0][b0+bOwn]
    float* outp = out + (size_t)(b0 + bOwn) * NDIM + rowOwn;

    __syncthreads();

    // per-thread A base; chunk (j,i) at At + i*NDIM + j*64
    const float* At = A + (size_t)rbase * NDIM + s * 4;

    for (int t = 0; t < LSTEPS; ++t) {
        const int cur = t & 1;

        // issue ALL 16 tri-masked A loads for this step up front (MLP)
        float4 ab[4][4];
#pragma unroll
        for (int j = 0; j < 4; ++j) {
            const int k0 = j * 64 + s * 4;
#pragma unroll
            for (int i = 0; i < 4; ++i) {
                ab[j][i] = make_float4(0.f, 0.f, 0.f, 0.f);
                if (k0 <= rbase + i)
                    ab[j][i] = *(const float4*)(At + i * NDIM + j * 64);
            }
        }
        At += NDIM * NDIM;

        // prefetch next-step scalars (latency hides under FMA/butterfly)
        const int tn = (t + 1 < LSTEPS) ? t + 1 : t;
        const float bst_n = Bst[tn * NDIM + rowOwn];
        const float inp_n = inp[tn * BATCH + b0 + bOwn];

        float acc[4][BB];
#pragma unroll
        for (int i = 0; i < 4; ++i)
#pragma unroll
            for (int b = 0; b < BB; ++b) acc[i][b] = 0.f;

#pragma unroll
        for (int j = 0; j < 4; ++j) {
            const int k0 = j * 64 + s * 4;
            const float4 xv0 = *(const float4*)&xs[cur][0][k0];
            const float4 xv1 = *(const float4*)&xs[cur][1][k0];
#pragma unroll
            for (int i = 0; i < 4; ++i) {
                const float4 a = ab[j][i];
                acc[i][0] = fmaf(a.x, xv0.x, acc[i][0]);
                acc[i][0] = fmaf(a.y, xv0.y, acc[i][0]);
                acc[i][0] = fmaf(a.z, xv0.z, acc[i][0]);
                acc[i][0] = fmaf(a.w, xv0.w, acc[i][0]);
                acc[i][1] = fmaf(a.x, xv1.x, acc[i][1]);
                acc[i][1] = fmaf(a.y, xv1.y, acc[i][1]);
                acc[i][1] = fmaf(a.z, xv1.z, acc[i][1]);
                acc[i][1] = fmaf(a.w, xv1.w, acc[i][1]);
            }
        }

        // 4-stage butterfly over the 16-lane group: sums the 16 k-segments and
        // redistributes so lane s holds the value for (rowOwn, bOwn).
        // stage 1 (xor 1): keep own batch, exchange the other
        float c[4];
#pragma unroll
        for (int i = 0; i < 4; ++i) {
            const float keep = bOwn ? acc[i][1] : acc[i][0];
            const float send = bOwn ? acc[i][0] : acc[i][1];
            c[i] = keep + __shfl_xor(send, 1);
        }
        // stage 2 (xor 2): keep rows with (r&1)==sel1
        float d[2];
#pragma unroll
        for (int m = 0; m < 2; ++m) {
            const float keep = c[2 * m + sel1];
            const float send = c[2 * m + (1 - sel1)];
            d[m] = keep + __shfl_xor(send, 2);
        }
        // stage 3 (xor 4): keep row with bit1==sel2
        const float e = d[sel2] + __shfl_xor(d[1 - sel2], 4);
        // stage 4 (xor 8): fold the other 8 k-segments (result duplicated)
        float v = e + __shfl_xor(e, 8);

        v = fmaf(inp_c, bst_c, v);

        if (writer) {
            xs[cur ^ 1][bOwn][rowOwn] = v;   // state for step t+1
            *outp = v;                        // out[t][b0+bOwn][rowOwn]
        }
        outp += BATCH * NDIM;
        bst_c = bst_n;
        inp_c = inp_n;

        // drain LDS writes only; A loads already consumed, out-store may linger
        asm volatile("s_waitcnt lgkmcnt(0)" ::: "memory");
        __builtin_amdgcn_s_barrier();
        asm volatile("" ::: "memory");
    }
}

extern "C" void kernel_launch(void* const* d_in, const int* in_sizes, int n_in,
                              void* d_out, int out_size, void* d_ws, size_t ws_size,
                              hipStream_t stream) {
    const float* inp = (const float*)d_in[0];  // (L, BATCH) f32
    const float* A   = (const float*)d_in[1];  // (L, N, N)  f32
    const float* Bst = (const float*)d_in[2];  // (L, N)     f32
    float* out = (float*)d_out;                // (L, BATCH, N) f32
    hipLaunchKernelGGL(hippo_scan, dim3(NWG), dim3(THREADS), 0, stream,
                       inp, A, Bst, out);
}